// Round 19
// baseline (289.528 us; speedup 1.0000x reference)
//
#include <hip/hip_runtime.h>
#include <stdint.h>

#define B_ 4
#define C_ 2048
#define L_ 4096
#define M_ 256
#define M3_ 768
#define SLOPE_ 0.2f
#define SPLIT_ 4
#define KVB_ 32

typedef __attribute__((ext_vector_type(8))) short short8;
typedef __attribute__((ext_vector_type(4))) float f32x4;
typedef __attribute__((ext_vector_type(16))) float f32x16;
typedef __attribute__((ext_vector_type(2))) int int2v;

__device__ __forceinline__ unsigned short f2bf(float f) {
    union { float f; unsigned u; } v; v.f = f;
    unsigned r = v.u + 0x7FFF + ((v.u >> 16) & 1);   // RNE
    return (unsigned short)(r >> 16);
}
__device__ __forceinline__ unsigned fbits(float f) {
    union { float f; unsigned u; } v; v.f = f; return v.u;
}
__device__ __forceinline__ unsigned pack2(float a, float b) {
    return (unsigned)f2bf(a) | ((unsigned)f2bf(b) << 16);
}
__device__ __forceinline__ float bf2f(unsigned short u) {
    union { unsigned u; float f; } v; v.u = (unsigned)u << 16; return v.f;
}
__device__ __forceinline__ float lrelu(float v) { return v >= 0.f ? v : SLOPE_ * v; }

__device__ __forceinline__ void gload_lds16(const void* g, void* l) {
    __builtin_amdgcn_global_load_lds(
        (const __attribute__((address_space(1))) void*)g,
        (__attribute__((address_space(3))) void*)l, 16, 0, 0);
}

// ---------------------------------------------------------------------------
// prep_x: x [B][C][L] fp32 -> xT [B][L][C] bf16 (unchanged).
// ---------------------------------------------------------------------------
__global__ __launch_bounds__(256) void prep_x(
    const float* __restrict__ x, unsigned short* __restrict__ xT)
{
    const int l = blockIdx.x * 64 + (threadIdx.x & 63);
    const int c = blockIdx.y * 32 + (threadIdx.x >> 6) * 8;
    const int b = blockIdx.z;
    const float* src = x + ((size_t)b * C_ + c) * L_ + l;
    unsigned v[4];
    #pragma unroll
    for (int j = 0; j < 4; ++j)
        v[j] = pack2(src[(size_t)(2 * j) * L_], src[(size_t)(2 * j + 1) * L_]);
    *reinterpret_cast<uint4*>(&xT[((size_t)b * L_ + l) * C_ + c]) =
        *reinterpret_cast<uint4*>(v);
}

// ---------------------------------------------------------------------------
// prep_w (unchanged).
// ---------------------------------------------------------------------------
__global__ __launch_bounds__(256) void prep_w(
    const float* __restrict__ Wt, const float* __restrict__ Wp,
    const float* __restrict__ Wg, const float* __restrict__ Wo,
    unsigned short* __restrict__ w3, unsigned short* __restrict__ wo)
{
    const size_t NW = (size_t)M_ * C_;
    size_t e = ((size_t)blockIdx.x * 256 + threadIdx.x) * 8;
    const float* src; unsigned short* dst;
    if (e < NW)          { src = Wt + e;          dst = w3 + e; }
    else if (e < 2 * NW) { src = Wp + (e - NW);   dst = w3 + e; }
    else if (e < 3 * NW) { src = Wg + (e - 2*NW); dst = w3 + e; }
    else                 { src = Wo + (e - 3*NW); dst = wo + (e - 3*NW); }
    float4 a = *reinterpret_cast<const float4*>(src);
    float4 b = *reinterpret_cast<const float4*>(src + 4);
    unsigned v[4] = { pack2(a.x, a.y), pack2(a.z, a.w),
                      pack2(b.x, b.y), pack2(b.z, b.w) };
    *reinterpret_cast<uint4*>(dst) = *reinterpret_cast<uint4*>(v);
}

// ---------------------------------------------------------------------------
// proj_kernel v5 (unchanged from round 17/18): epilogue writes
//   theta -> theta_cm [B][mc<32][L][8], phi row-major (pre-scaled 1/32),
//   gamma -> gamma_v  [B][kc<512][M][8].
// ---------------------------------------------------------------------------
__global__ __launch_bounds__(256, 3) void proj_kernel(
    const unsigned short* __restrict__ w3,
    const float* __restrict__ bt, const float* __restrict__ bp,
    const float* __restrict__ bg,
    const unsigned short* __restrict__ xT,
    unsigned short* __restrict__ theta,
    unsigned short* __restrict__ phi,
    unsigned short* __restrict__ gammaT)
{
    __shared__ unsigned short As[128 * 64];
    __shared__ unsigned short Bs[128 * 64];

    const int l0 = blockIdx.x * 128;
    const int m0 = blockIdx.y * 128;
    const int b  = blockIdx.z;
    const int t  = threadIdx.x;
    const int wave = t >> 6, lane = t & 63;
    const int lr = lane & 15, lg = lane >> 4;
    const int wm = (wave >> 1) * 64, wl = (wave & 1) * 64;

    const int which = m0 >> 8;
    const float* bsrc = (which == 0) ? bt : (which == 1) ? bp : bg;
    const int mw = m0 & 255;

    const unsigned short* abase = w3 + (size_t)m0 * C_;
    const unsigned short* bbase = xT + ((size_t)b * L_ + l0) * C_;

    const int srow = lane >> 3;
    const int scol = ((lane & 7) ^ srow) * 8;

    f32x4 acc[4][4] = {};

    for (int k0 = 0; k0 < C_; k0 += 64) {
        __syncthreads();
        #pragma unroll
        for (int i = 0; i < 4; ++i) {
            int chunk = wave * 4 + i;
            int row = chunk * 8 + srow;
            gload_lds16(abase + (size_t)row * C_ + k0 + scol, As + chunk * 512);
            gload_lds16(bbase + (size_t)row * C_ + k0 + scol, Bs + chunk * 512);
        }
        __syncthreads();

        #pragma unroll
        for (int ks = 0; ks < 2; ++ks) {
            short8 af[4], bf[4];
            #pragma unroll
            for (int mi = 0; mi < 4; ++mi)
                af[mi] = *reinterpret_cast<const short8*>(
                    &As[(wm + mi * 16 + lr) * 64 +
                        ((ks * 32 + lg * 8) ^ ((lr & 7) << 3))]);
            #pragma unroll
            for (int ni = 0; ni < 4; ++ni)
                bf[ni] = *reinterpret_cast<const short8*>(
                    &Bs[(wl + ni * 16 + lr) * 64 +
                        ((ks * 32 + lg * 8) ^ ((lr & 7) << 3))]);
            #pragma unroll
            for (int mi = 0; mi < 4; ++mi)
                #pragma unroll
                for (int ni = 0; ni < 4; ++ni)
                    acc[mi][ni] = __builtin_amdgcn_mfma_f32_16x16x32_bf16(
                        af[mi], bf[ni], acc[mi][ni], 0, 0, 0);
        }
    }

    if (which == 0) {
        #pragma unroll
        for (int mi = 0; mi < 4; ++mi) {
            const int mloc = mw + wm + mi * 16 + lg * 4;
            float b0 = bsrc[mloc], b1 = bsrc[mloc + 1];
            float b2 = bsrc[mloc + 2], b3 = bsrc[mloc + 3];
            const size_t cmbase = ((size_t)(b * 32 + (mloc >> 3)) * L_) * 8 + (mloc & 7);
            #pragma unroll
            for (int ni = 0; ni < 4; ++ni) {
                int l = l0 + wl + ni * 16 + lr;
                uint2 pk;
                pk.x = pack2(lrelu(acc[mi][ni][0] + b0), lrelu(acc[mi][ni][1] + b1));
                pk.y = pack2(lrelu(acc[mi][ni][2] + b2), lrelu(acc[mi][ni][3] + b3));
                *reinterpret_cast<uint2*>(&theta[cmbase + (size_t)l * 8]) = pk;
            }
        }
    } else if (which == 1) {
        #pragma unroll
        for (int mi = 0; mi < 4; ++mi) {
            const int mloc = mw + wm + mi * 16 + lg * 4;
            float b0 = bsrc[mloc], b1 = bsrc[mloc + 1];
            float b2 = bsrc[mloc + 2], b3 = bsrc[mloc + 3];
            #pragma unroll
            for (int ni = 0; ni < 4; ++ni) {
                int l = l0 + wl + ni * 16 + lr;
                uint2 pk;
                pk.x = pack2(lrelu(acc[mi][ni][0] + b0) * 0.03125f,
                             lrelu(acc[mi][ni][1] + b1) * 0.03125f);
                pk.y = pack2(lrelu(acc[mi][ni][2] + b2) * 0.03125f,
                             lrelu(acc[mi][ni][3] + b3) * 0.03125f);
                *reinterpret_cast<uint2*>(&phi[((size_t)b * L_ + l) * M_ + mloc]) = pk;
            }
        }
    } else {
        #pragma unroll
        for (int mi = 0; mi < 4; ++mi) {
            #pragma unroll
            for (int r = 0; r < 4; ++r) {
                int m = mw + wm + mi * 16 + lg * 4 + r;
                float bias = bsrc[m];
                #pragma unroll
                for (int ni = 0; ni < 4; ++ni) {
                    int l = l0 + wl + ni * 16 + lr;
                    gammaT[((size_t)(b * 512 + (l >> 3)) * M_ + m) * 8 + (l & 7)] =
                        f2bf(lrelu(acc[mi][ni][r] + bias));
                }
            }
        }
    }
}

// ---------------------------------------------------------------------------
// attn v14 (unchanged from round 18): 4-wave blocks, QBLK=128, 2 blocks/CU,
// chunk-major global+LDS layouts, dbuf gload_lds, in-register P, XCD swizzle.
// ---------------------------------------------------------------------------
__global__ __launch_bounds__(256, 2) void attn_kernel(
    const unsigned short* __restrict__ phi,     // pre-scaled by 1/32
    const unsigned short* __restrict__ theta,   // theta_cm [B][32][L][8]
    const unsigned short* __restrict__ gammaT,  // gamma_v  [B][512][M][8]
    unsigned short* __restrict__ yp,            // [SPLIT][B][L][M] bf16
    float* __restrict__ rsp)
{
    __shared__ unsigned short Ks[2][KVB_ * 256];
    __shared__ unsigned short Vs[2][256 * KVB_];

    const int flat = blockIdx.x + 32 * (blockIdx.y + 4 * blockIdx.z);
    const int fs   = (flat & 7) * 64 + (flat >> 3);     // bijective on [0,512)
    const int q0 = (fs & 31) * 128;
    const int sb = fs >> 5;
    const int s  = sb & 3;
    const int b  = sb >> 2;
    const int kvbase = s * (L_ / SPLIT_);
    const int t  = threadIdx.x;                         // < 256
    const int wave = t >> 6, lane = t & 63;
    const int l31 = lane & 31, h = lane >> 5;

    const unsigned short* theta_b = theta  + (size_t)b * L_ * M_;   // [32][L][8]
    const unsigned short* gamma_b = gammaT + (size_t)b * M_ * L_;   // [512][M][8]

    short8 qf[16];
    {
        const unsigned short* qrow =
            phi + ((size_t)b * L_ + q0 + wave * 32 + l31) * M_ + h * 8;
        #pragma unroll
        for (int st = 0; st < 16; ++st)
            qf[st] = *reinterpret_cast<const short8*>(qrow + st * 16);
    }

    f32x16 accy[8] = {};
    float rsum = 0.f;

    auto stage_k = [&](unsigned short* buf, int kv0) {
        #pragma unroll
        for (int q = 0; q < 4; ++q) {
            int p = q * 256 + t;
            int mc = p >> 5, row = p & 31;
            const unsigned short* src =
                theta_b + ((size_t)mc * L_ + kv0 + row) * 8;
            gload_lds16(src, buf + ((size_t)(q * 256 + wave * 64) << 3));
        }
    };
    auto stage_v = [&](unsigned short* buf, int kv0) {
        #pragma unroll
        for (int q = 0; q < 4; ++q) {
            int p = q * 256 + t;
            int kc = p >> 8, m = p & 255;
            const unsigned short* src =
                gamma_b + ((size_t)(kv0 / 8 + kc) * M_ + m) * 8;
            gload_lds16(src, buf + ((size_t)(q * 256 + wave * 64) << 3));
        }
    };

    stage_k(&Ks[0][0], kvbase);
    stage_v(&Vs[0][0], kvbase);
    __syncthreads();

    int cur = 0;
    for (int it = 0; it < L_ / SPLIT_ / KVB_; ++it) {
        if (it + 1 < L_ / SPLIT_ / KVB_) {
            stage_k(&Ks[cur ^ 1][0], kvbase + (it + 1) * KVB_);
            stage_v(&Vs[cur ^ 1][0], kvbase + (it + 1) * KVB_);
        }

        f32x16 sacc = {};
        __builtin_amdgcn_s_setprio(1);
        #pragma unroll
        for (int st = 0; st < 16; ++st) {
            short8 kf = *reinterpret_cast<const short8*>(
                &Ks[cur][(st * 2 + h) * 256 + l31 * 8]);
            sacc = __builtin_amdgcn_mfma_f32_32x32x16_bf16(kf, qf[st], sacc, 0, 0, 0);
        }
        __builtin_amdgcn_s_setprio(0);

        unsigned d[8];
        #pragma unroll
        for (int i = 0; i < 8; ++i) {
            float p0 = __expf(sacc[2 * i]);
            float p1 = __expf(sacc[2 * i + 1]);
            rsum += p0 + p1;
            d[i] = __builtin_amdgcn_perm(fbits(p1), fbits(p0), 0x07060302u);
        }
        short8 paf[2];
        #pragma unroll
        for (int s2 = 0; s2 < 2; ++s2) {
            int2v r0 = __builtin_amdgcn_permlane32_swap(
                (int)d[4 * s2], (int)d[4 * s2 + 2], false, false);
            int2v r1 = __builtin_amdgcn_permlane32_swap(
                (int)d[4 * s2 + 1], (int)d[4 * s2 + 3], false, false);
            unsigned w[4] = { (unsigned)r0.x, (unsigned)r1.x,
                              (unsigned)r0.y, (unsigned)r1.y };
            paf[s2] = *reinterpret_cast<short8*>(w);
        }

        __builtin_amdgcn_s_setprio(1);
        #pragma unroll
        for (int mt = 0; mt < 8; ++mt) {
            #pragma unroll
            for (int s2 = 0; s2 < 2; ++s2) {
                short8 vf = *reinterpret_cast<const short8*>(
                    &Vs[cur][(s2 * 2 + h) * 2048 + (mt * 32 + l31) * 8]);
                accy[mt] = __builtin_amdgcn_mfma_f32_32x32x16_bf16(
                    paf[s2], vf, accy[mt], 0, 0, 0);
            }
        }
        __builtin_amdgcn_s_setprio(0);

        __syncthreads();
        cur ^= 1;
    }

    unsigned short* ypb = yp + (((size_t)(s * B_ + b) * L_) + q0) * M_;
    float tot = rsum + __shfl_xor(rsum, 32, 64);
    if (h == 0)
        rsp[((size_t)(s * B_ + b) * L_) + q0 + wave * 32 + l31] = tot;
    #pragma unroll
    for (int mt = 0; mt < 8; ++mt) {
        #pragma unroll
        for (int r = 0; r < 16; ++r) {
            int q = wave * 32 + (r & 3) + 8 * (r >> 2) + 4 * h;
            ypb[(size_t)q * M_ + mt * 32 + l31] = f2bf(accy[mt][r]);
        }
    }
}

// ---------------------------------------------------------------------------
// out_kernel v5: reduce fused in.  B operand built by reg-staging the 4 yp
// partials + rsp normalization, ds_write_b128 with the read-side XOR map.
// A tile staged via gload_lds as before.  grid (32, 16, 4), block 256.
// ---------------------------------------------------------------------------
__global__ __launch_bounds__(256, 3) void out_kernel(
    const float* __restrict__ x,
    const unsigned short* __restrict__ wo,
    const float* __restrict__ bo,
    const unsigned short* __restrict__ yp,   // [SPLIT][B][L][M] bf16 partials
    const float* __restrict__ rsp,           // [SPLIT][B][L] fp32 row sums
    float* __restrict__ out)
{
    __shared__ unsigned short As[128 * 64];
    __shared__ unsigned short Bs[128 * 64];

    const int l0 = blockIdx.x * 128;
    const int c0 = blockIdx.y * 128;
    const int b  = blockIdx.z;
    const int t  = threadIdx.x;
    const int wave = t >> 6, lane = t & 63;
    const int lr = lane & 15, lg = lane >> 4;
    const int wm = (wave >> 1) * 64, wl = (wave & 1) * 64;

    const unsigned short* abase = wo + (size_t)c0 * M_;

    const int srow = lane >> 3;
    const int scol = ((lane & 7) ^ srow) * 8;

    // per-thread B rows are k0-invariant: p = q*256 + t -> row = p>>3
    float inv[4];
    #pragma unroll
    for (int q = 0; q < 4; ++q) {
        int row = (q * 256 + t) >> 3;
        float rs = 0.f;
        #pragma unroll
        for (int s = 0; s < SPLIT_; ++s)
            rs += rsp[((size_t)(s * B_ + b) * L_) + l0 + row];
        inv[q] = 1.f / rs;
    }

    f32x4 acc[4][4] = {};

    for (int k0 = 0; k0 < M_; k0 += 64) {
        __syncthreads();
        // A: Wo tile via async gload_lds (latency overlaps B reg-staging)
        #pragma unroll
        for (int i = 0; i < 4; ++i) {
            int chunk = wave * 4 + i;
            int row = chunk * 8 + srow;
            gload_lds16(abase + (size_t)row * M_ + k0 + scol, As + chunk * 512);
        }
        // B: sum 4 yp partials, normalize, bf16, ds_write with XOR map
        #pragma unroll
        for (int q = 0; q < 4; ++q) {
            int p = q * 256 + t;
            int row = p >> 3, c8 = p & 7;
            float a8[8] = {};
            #pragma unroll
            for (int s = 0; s < SPLIT_; ++s) {
                uint4 raw = *reinterpret_cast<const uint4*>(
                    &yp[(((size_t)(s * B_ + b) * L_) + l0 + row) * M_ + k0 + c8 * 8]);
                const unsigned* dw = reinterpret_cast<const unsigned*>(&raw);
                #pragma unroll
                for (int k = 0; k < 4; ++k) {
                    a8[2 * k]     += bf2f((unsigned short)(dw[k] & 0xFFFF));
                    a8[2 * k + 1] += bf2f((unsigned short)(dw[k] >> 16));
                }
            }
            unsigned v[4];
            #pragma unroll
            for (int k = 0; k < 4; ++k)
                v[k] = pack2(a8[2 * k] * inv[q], a8[2 * k + 1] * inv[q]);
            *reinterpret_cast<uint4*>(
                &Bs[row * 64 + ((c8 * 8) ^ ((row & 7) << 3))]) =
                *reinterpret_cast<uint4*>(v);
        }
        __syncthreads();

        #pragma unroll
        for (int ks = 0; ks < 2; ++ks) {
            short8 af[4], bf[4];
            #pragma unroll
            for (int mi = 0; mi < 4; ++mi)
                af[mi] = *reinterpret_cast<const short8*>(
                    &As[(wm + mi * 16 + lr) * 64 +
                        ((ks * 32 + lg * 8) ^ ((lr & 7) << 3))]);
            #pragma unroll
            for (int ni = 0; ni < 4; ++ni)
                bf[ni] = *reinterpret_cast<const short8*>(
                    &Bs[(wl + ni * 16 + lr) * 64 +
                        ((ks * 32 + lg * 8) ^ ((lr & 7) << 3))]);
            #pragma unroll
            for (int mi = 0; mi < 4; ++mi)
                #pragma unroll
                for (int ni = 0; ni < 4; ++ni)
                    acc[mi][ni] = __builtin_amdgcn_mfma_f32_16x16x32_bf16(
                        af[mi], bf[ni], acc[mi][ni], 0, 0, 0);
        }
    }

    #pragma unroll
    for (int mi = 0; mi < 4; ++mi) {
        #pragma unroll
        for (int r = 0; r < 4; ++r) {
            int c = c0 + wm + mi * 16 + lg * 4 + r;
            float bias = bo[c];
            #pragma unroll
            for (int ni = 0; ni < 4; ++ni) {
                int l = l0 + wl + ni * 16 + lr;
                size_t idx = ((size_t)b * C_ + c) * L_ + l;
                out[idx] = x[idx] + lrelu(acc[mi][ni][r] + bias);
            }
        }
    }
}

// ---------------------------------------------------------------------------
extern "C" void kernel_launch(void* const* d_in, const int* in_sizes, int n_in,
                              void* d_out, int out_size, void* d_ws, size_t ws_size,
                              hipStream_t stream) {
    const float* x  = (const float*)d_in[0];
    const float* Wt = (const float*)d_in[1];
    const float* bt = (const float*)d_in[2];
    const float* Wp = (const float*)d_in[3];
    const float* bp = (const float*)d_in[4];
    const float* Wg = (const float*)d_in[5];
    const float* bg = (const float*)d_in[6];
    const float* Wo = (const float*)d_in[7];
    const float* bo = (const float*)d_in[8];
    float* out = (float*)d_out;

    unsigned short* xT    = (unsigned short*)d_ws;                  // [B][L][C]  64MB
    unsigned short* w3    = xT + (size_t)B_ * L_ * C_;              // [768][C]   3MB
    unsigned short* wob   = w3 + (size_t)M3_ * C_;                  // [C][M]     1MB
    unsigned short* theta = wob + (size_t)C_ * M_;                  // theta_cm   8MB
    unsigned short* phi   = theta + (size_t)B_ * L_ * M_;           // [B][L][M]  8MB
    unsigned short* gammaT= phi   + (size_t)B_ * L_ * M_;           // gamma_v    8MB

    unsigned short* yp = xT;     // [SPLIT][B][L][M] bf16, 32MB (xT dead after proj)
    float* rsp = (float*)w3;     // [SPLIT][B][L]    fp32 (w3 dead after proj)

    prep_x<<<dim3(L_ / 64, C_ / 32, B_), 256, 0, stream>>>(x, xT);
    prep_w<<<dim3(2097152 / 8 / 256), 256, 0, stream>>>(Wt, Wp, Wg, Wo, w3, wob);
    proj_kernel<<<dim3(L_ / 128, M3_ / 128, B_), 256, 0, stream>>>(
        w3, bt, bp, bg, xT, theta, phi, gammaT);
    attn_kernel<<<dim3(L_ / 128, SPLIT_, B_), 256, 0, stream>>>(
        phi, theta, gammaT, yp, rsp);
    out_kernel<<<dim3(L_ / 128, C_ / 128, B_), 256, 0, stream>>>(
        x, wob, bo, yp, rsp, out);
}

// Round 20
// 249.297 us; speedup vs baseline: 1.1614x; 1.1614x over previous
//
#include <hip/hip_runtime.h>
#include <stdint.h>

#define B_ 4
#define C_ 2048
#define L_ 4096
#define M_ 256
#define M3_ 768
#define SLOPE_ 0.2f
#define SPLIT_ 4
#define KVB_ 32

typedef __attribute__((ext_vector_type(8))) short short8;
typedef __attribute__((ext_vector_type(4))) float f32x4;
typedef __attribute__((ext_vector_type(16))) float f32x16;
typedef __attribute__((ext_vector_type(2))) int int2v;

__device__ __forceinline__ unsigned short f2bf(float f) {
    union { float f; unsigned u; } v; v.f = f;
    unsigned r = v.u + 0x7FFF + ((v.u >> 16) & 1);   // RNE
    return (unsigned short)(r >> 16);
}
__device__ __forceinline__ unsigned fbits(float f) {
    union { float f; unsigned u; } v; v.f = f; return v.u;
}
__device__ __forceinline__ unsigned pack2(float a, float b) {
    return (unsigned)f2bf(a) | ((unsigned)f2bf(b) << 16);
}
__device__ __forceinline__ float bf2f(unsigned short u) {
    union { unsigned u; float f; } v; v.u = (unsigned)u << 16; return v.f;
}
__device__ __forceinline__ float lrelu(float v) { return v >= 0.f ? v : SLOPE_ * v; }

__device__ __forceinline__ void gload_lds16(const void* g, void* l) {
    __builtin_amdgcn_global_load_lds(
        (const __attribute__((address_space(1))) void*)g,
        (__attribute__((address_space(3))) void*)l, 16, 0, 0);
}

// ---------------------------------------------------------------------------
// prep_x: x [B][C][L] fp32 -> xT [B][L][C] bf16.
// ---------------------------------------------------------------------------
__global__ __launch_bounds__(256) void prep_x(
    const float* __restrict__ x, unsigned short* __restrict__ xT)
{
    const int l = blockIdx.x * 64 + (threadIdx.x & 63);
    const int c = blockIdx.y * 32 + (threadIdx.x >> 6) * 8;
    const int b = blockIdx.z;
    const float* src = x + ((size_t)b * C_ + c) * L_ + l;
    unsigned v[4];
    #pragma unroll
    for (int j = 0; j < 4; ++j)
        v[j] = pack2(src[(size_t)(2 * j) * L_], src[(size_t)(2 * j + 1) * L_]);
    *reinterpret_cast<uint4*>(&xT[((size_t)b * L_ + l) * C_ + c]) =
        *reinterpret_cast<uint4*>(v);
}

// ---------------------------------------------------------------------------
// prep_w: W_t|W_p|W_g -> w3 bf16 ; W_o -> wo bf16.
// ---------------------------------------------------------------------------
__global__ __launch_bounds__(256) void prep_w(
    const float* __restrict__ Wt, const float* __restrict__ Wp,
    const float* __restrict__ Wg, const float* __restrict__ Wo,
    unsigned short* __restrict__ w3, unsigned short* __restrict__ wo)
{
    const size_t NW = (size_t)M_ * C_;
    size_t e = ((size_t)blockIdx.x * 256 + threadIdx.x) * 8;
    const float* src; unsigned short* dst;
    if (e < NW)          { src = Wt + e;          dst = w3 + e; }
    else if (e < 2 * NW) { src = Wp + (e - NW);   dst = w3 + e; }
    else if (e < 3 * NW) { src = Wg + (e - 2*NW); dst = w3 + e; }
    else                 { src = Wo + (e - 3*NW); dst = wo + (e - 3*NW); }
    float4 a = *reinterpret_cast<const float4*>(src);
    float4 b = *reinterpret_cast<const float4*>(src + 4);
    unsigned v[4] = { pack2(a.x, a.y), pack2(a.z, a.w),
                      pack2(b.x, b.y), pack2(b.z, b.w) };
    *reinterpret_cast<uint4*>(dst) = *reinterpret_cast<uint4*>(v);
}

// ---------------------------------------------------------------------------
// proj_kernel v5: m97 single-buffer loop, LB(256,3), both-sides XOR swizzle.
// Epilogue: theta -> theta_cm [B][mc<32][L][8]; phi row-major (pre-scaled
// 1/32); gamma -> gamma_v [B][kc<512][M][8].
// ---------------------------------------------------------------------------
__global__ __launch_bounds__(256, 3) void proj_kernel(
    const unsigned short* __restrict__ w3,
    const float* __restrict__ bt, const float* __restrict__ bp,
    const float* __restrict__ bg,
    const unsigned short* __restrict__ xT,
    unsigned short* __restrict__ theta,
    unsigned short* __restrict__ phi,
    unsigned short* __restrict__ gammaT)
{
    __shared__ unsigned short As[128 * 64];
    __shared__ unsigned short Bs[128 * 64];

    const int l0 = blockIdx.x * 128;
    const int m0 = blockIdx.y * 128;
    const int b  = blockIdx.z;
    const int t  = threadIdx.x;
    const int wave = t >> 6, lane = t & 63;
    const int lr = lane & 15, lg = lane >> 4;
    const int wm = (wave >> 1) * 64, wl = (wave & 1) * 64;

    const int which = m0 >> 8;
    const float* bsrc = (which == 0) ? bt : (which == 1) ? bp : bg;
    const int mw = m0 & 255;

    const unsigned short* abase = w3 + (size_t)m0 * C_;
    const unsigned short* bbase = xT + ((size_t)b * L_ + l0) * C_;

    const int srow = lane >> 3;
    const int scol = ((lane & 7) ^ srow) * 8;

    f32x4 acc[4][4] = {};

    for (int k0 = 0; k0 < C_; k0 += 64) {
        __syncthreads();
        #pragma unroll
        for (int i = 0; i < 4; ++i) {
            int chunk = wave * 4 + i;
            int row = chunk * 8 + srow;
            gload_lds16(abase + (size_t)row * C_ + k0 + scol, As + chunk * 512);
            gload_lds16(bbase + (size_t)row * C_ + k0 + scol, Bs + chunk * 512);
        }
        __syncthreads();

        #pragma unroll
        for (int ks = 0; ks < 2; ++ks) {
            short8 af[4], bf[4];
            #pragma unroll
            for (int mi = 0; mi < 4; ++mi)
                af[mi] = *reinterpret_cast<const short8*>(
                    &As[(wm + mi * 16 + lr) * 64 +
                        ((ks * 32 + lg * 8) ^ ((lr & 7) << 3))]);
            #pragma unroll
            for (int ni = 0; ni < 4; ++ni)
                bf[ni] = *reinterpret_cast<const short8*>(
                    &Bs[(wl + ni * 16 + lr) * 64 +
                        ((ks * 32 + lg * 8) ^ ((lr & 7) << 3))]);
            #pragma unroll
            for (int mi = 0; mi < 4; ++mi)
                #pragma unroll
                for (int ni = 0; ni < 4; ++ni)
                    acc[mi][ni] = __builtin_amdgcn_mfma_f32_16x16x32_bf16(
                        af[mi], bf[ni], acc[mi][ni], 0, 0, 0);
        }
    }

    if (which == 0) {
        #pragma unroll
        for (int mi = 0; mi < 4; ++mi) {
            const int mloc = mw + wm + mi * 16 + lg * 4;
            float b0 = bsrc[mloc], b1 = bsrc[mloc + 1];
            float b2 = bsrc[mloc + 2], b3 = bsrc[mloc + 3];
            const size_t cmbase = ((size_t)(b * 32 + (mloc >> 3)) * L_) * 8 + (mloc & 7);
            #pragma unroll
            for (int ni = 0; ni < 4; ++ni) {
                int l = l0 + wl + ni * 16 + lr;
                uint2 pk;
                pk.x = pack2(lrelu(acc[mi][ni][0] + b0), lrelu(acc[mi][ni][1] + b1));
                pk.y = pack2(lrelu(acc[mi][ni][2] + b2), lrelu(acc[mi][ni][3] + b3));
                *reinterpret_cast<uint2*>(&theta[cmbase + (size_t)l * 8]) = pk;
            }
        }
    } else if (which == 1) {
        #pragma unroll
        for (int mi = 0; mi < 4; ++mi) {
            const int mloc = mw + wm + mi * 16 + lg * 4;
            float b0 = bsrc[mloc], b1 = bsrc[mloc + 1];
            float b2 = bsrc[mloc + 2], b3 = bsrc[mloc + 3];
            #pragma unroll
            for (int ni = 0; ni < 4; ++ni) {
                int l = l0 + wl + ni * 16 + lr;
                uint2 pk;
                pk.x = pack2(lrelu(acc[mi][ni][0] + b0) * 0.03125f,
                             lrelu(acc[mi][ni][1] + b1) * 0.03125f);
                pk.y = pack2(lrelu(acc[mi][ni][2] + b2) * 0.03125f,
                             lrelu(acc[mi][ni][3] + b3) * 0.03125f);
                *reinterpret_cast<uint2*>(&phi[((size_t)b * L_ + l) * M_ + mloc]) = pk;
            }
        }
    } else {
        #pragma unroll
        for (int mi = 0; mi < 4; ++mi) {
            #pragma unroll
            for (int r = 0; r < 4; ++r) {
                int m = mw + wm + mi * 16 + lg * 4 + r;
                float bias = bsrc[m];
                #pragma unroll
                for (int ni = 0; ni < 4; ++ni) {
                    int l = l0 + wl + ni * 16 + lr;
                    gammaT[((size_t)(b * 512 + (l >> 3)) * M_ + m) * 8 + (l & 7)] =
                        f2bf(lrelu(acc[mi][ni][r] + bias));
                }
            }
        }
    }
}

// ---------------------------------------------------------------------------
// attn v14: 4-wave blocks, QBLK=128, 2 blocks/CU, chunk-major global+LDS
// layouts (0 bank conflicts), dbuf gload_lds, in-register P, XCD swizzle.
// ---------------------------------------------------------------------------
__global__ __launch_bounds__(256, 2) void attn_kernel(
    const unsigned short* __restrict__ phi,     // pre-scaled by 1/32
    const unsigned short* __restrict__ theta,   // theta_cm [B][32][L][8]
    const unsigned short* __restrict__ gammaT,  // gamma_v  [B][512][M][8]
    unsigned short* __restrict__ yp,            // [SPLIT][B][L][M] bf16
    float* __restrict__ rsp)
{
    __shared__ unsigned short Ks[2][KVB_ * 256];
    __shared__ unsigned short Vs[2][256 * KVB_];

    const int flat = blockIdx.x + 32 * (blockIdx.y + 4 * blockIdx.z);
    const int fs   = (flat & 7) * 64 + (flat >> 3);     // bijective on [0,512)
    const int q0 = (fs & 31) * 128;
    const int sb = fs >> 5;
    const int s  = sb & 3;
    const int b  = sb >> 2;
    const int kvbase = s * (L_ / SPLIT_);
    const int t  = threadIdx.x;                         // < 256
    const int wave = t >> 6, lane = t & 63;
    const int l31 = lane & 31, h = lane >> 5;

    const unsigned short* theta_b = theta  + (size_t)b * L_ * M_;   // [32][L][8]
    const unsigned short* gamma_b = gammaT + (size_t)b * M_ * L_;   // [512][M][8]

    short8 qf[16];
    {
        const unsigned short* qrow =
            phi + ((size_t)b * L_ + q0 + wave * 32 + l31) * M_ + h * 8;
        #pragma unroll
        for (int st = 0; st < 16; ++st)
            qf[st] = *reinterpret_cast<const short8*>(qrow + st * 16);
    }

    f32x16 accy[8] = {};
    float rsum = 0.f;

    auto stage_k = [&](unsigned short* buf, int kv0) {
        #pragma unroll
        for (int q = 0; q < 4; ++q) {
            int p = q * 256 + t;
            int mc = p >> 5, row = p & 31;
            const unsigned short* src =
                theta_b + ((size_t)mc * L_ + kv0 + row) * 8;
            gload_lds16(src, buf + ((size_t)(q * 256 + wave * 64) << 3));
        }
    };
    auto stage_v = [&](unsigned short* buf, int kv0) {
        #pragma unroll
        for (int q = 0; q < 4; ++q) {
            int p = q * 256 + t;
            int kc = p >> 8, m = p & 255;
            const unsigned short* src =
                gamma_b + ((size_t)(kv0 / 8 + kc) * M_ + m) * 8;
            gload_lds16(src, buf + ((size_t)(q * 256 + wave * 64) << 3));
        }
    };

    stage_k(&Ks[0][0], kvbase);
    stage_v(&Vs[0][0], kvbase);
    __syncthreads();

    int cur = 0;
    for (int it = 0; it < L_ / SPLIT_ / KVB_; ++it) {
        if (it + 1 < L_ / SPLIT_ / KVB_) {
            stage_k(&Ks[cur ^ 1][0], kvbase + (it + 1) * KVB_);
            stage_v(&Vs[cur ^ 1][0], kvbase + (it + 1) * KVB_);
        }

        f32x16 sacc = {};
        __builtin_amdgcn_s_setprio(1);
        #pragma unroll
        for (int st = 0; st < 16; ++st) {
            short8 kf = *reinterpret_cast<const short8*>(
                &Ks[cur][(st * 2 + h) * 256 + l31 * 8]);
            sacc = __builtin_amdgcn_mfma_f32_32x32x16_bf16(kf, qf[st], sacc, 0, 0, 0);
        }
        __builtin_amdgcn_s_setprio(0);

        unsigned d[8];
        #pragma unroll
        for (int i = 0; i < 8; ++i) {
            float p0 = __expf(sacc[2 * i]);
            float p1 = __expf(sacc[2 * i + 1]);
            rsum += p0 + p1;
            d[i] = __builtin_amdgcn_perm(fbits(p1), fbits(p0), 0x07060302u);
        }
        short8 paf[2];
        #pragma unroll
        for (int s2 = 0; s2 < 2; ++s2) {
            int2v r0 = __builtin_amdgcn_permlane32_swap(
                (int)d[4 * s2], (int)d[4 * s2 + 2], false, false);
            int2v r1 = __builtin_amdgcn_permlane32_swap(
                (int)d[4 * s2 + 1], (int)d[4 * s2 + 3], false, false);
            unsigned w[4] = { (unsigned)r0.x, (unsigned)r1.x,
                              (unsigned)r0.y, (unsigned)r1.y };
            paf[s2] = *reinterpret_cast<short8*>(w);
        }

        __builtin_amdgcn_s_setprio(1);
        #pragma unroll
        for (int mt = 0; mt < 8; ++mt) {
            #pragma unroll
            for (int s2 = 0; s2 < 2; ++s2) {
                short8 vf = *reinterpret_cast<const short8*>(
                    &Vs[cur][(s2 * 2 + h) * 2048 + (mt * 32 + l31) * 8]);
                accy[mt] = __builtin_amdgcn_mfma_f32_32x32x16_bf16(
                    paf[s2], vf, accy[mt], 0, 0, 0);
            }
        }
        __builtin_amdgcn_s_setprio(0);

        __syncthreads();
        cur ^= 1;
    }

    unsigned short* ypb = yp + (((size_t)(s * B_ + b) * L_) + q0) * M_;
    float tot = rsum + __shfl_xor(rsum, 32, 64);
    if (h == 0)
        rsp[((size_t)(s * B_ + b) * L_) + q0 + wave * 32 + l31] = tot;
    #pragma unroll
    for (int mt = 0; mt < 8; ++mt) {
        #pragma unroll
        for (int r = 0; r < 16; ++r) {
            int q = wave * 32 + (r & 3) + 8 * (r >> 2) + 4 * h;
            ypb[(size_t)q * M_ + mt * 32 + l31] = f2bf(accy[mt][r]);
        }
    }
}

// ---------------------------------------------------------------------------
// reduce_kernel: bf16 partials in, bf16 y out.
// ---------------------------------------------------------------------------
__global__ __launch_bounds__(256) void reduce_kernel(
    const unsigned short* __restrict__ yp,
    const float* __restrict__ rsp,
    unsigned short* __restrict__ y)
{
    const int idx = blockIdx.x * 256 + threadIdx.x;
    const int ml  = (idx * 8) & (M_ - 1);
    const int row = (idx * 8) >> 8;
    const int b   = row >> 12;
    const int l   = row & (L_ - 1);

    float acc[8] = {};
    float rs = 0.f;
    #pragma unroll
    for (int s = 0; s < SPLIT_; ++s) {
        uint4 raw = *reinterpret_cast<const uint4*>(
            &yp[(((size_t)(s * B_ + b) * L_) + l) * M_ + ml]);
        const unsigned* dw = reinterpret_cast<const unsigned*>(&raw);
        #pragma unroll
        for (int k = 0; k < 4; ++k) {
            acc[2 * k]     += bf2f((unsigned short)(dw[k] & 0xFFFF));
            acc[2 * k + 1] += bf2f((unsigned short)(dw[k] >> 16));
        }
        rs += rsp[((size_t)(s * B_ + b) * L_) + l];
    }
    float inv = 1.f / rs;
    unsigned v[4] = { pack2(acc[0] * inv, acc[1] * inv),
                      pack2(acc[2] * inv, acc[3] * inv),
                      pack2(acc[4] * inv, acc[5] * inv),
                      pack2(acc[6] * inv, acc[7] * inv) };
    *reinterpret_cast<uint4*>(&y[((size_t)b * L_ + l) * M_ + ml]) =
        *reinterpret_cast<uint4*>(v);
}

// ---------------------------------------------------------------------------
// out_kernel v4: single-buffer m97 2-barrier + swizzle, LB(256,3).
// ---------------------------------------------------------------------------
__global__ __launch_bounds__(256, 3) void out_kernel(
    const float* __restrict__ x,
    const unsigned short* __restrict__ wo,
    const float* __restrict__ bo,
    const unsigned short* __restrict__ y,
    float* __restrict__ out)
{
    __shared__ unsigned short As[128 * 64];
    __shared__ unsigned short Bs[128 * 64];

    const int l0 = blockIdx.x * 128;
    const int c0 = blockIdx.y * 128;
    const int b  = blockIdx.z;
    const int t  = threadIdx.x;
    const int wave = t >> 6, lane = t & 63;
    const int lr = lane & 15, lg = lane >> 4;
    const int wm = (wave >> 1) * 64, wl = (wave & 1) * 64;

    const unsigned short* abase = wo + (size_t)c0 * M_;
    const unsigned short* bbase = y + ((size_t)b * L_ + l0) * M_;

    const int srow = lane >> 3;
    const int scol = ((lane & 7) ^ srow) * 8;

    f32x4 acc[4][4] = {};

    for (int k0 = 0; k0 < M_; k0 += 64) {
        __syncthreads();
        #pragma unroll
        for (int i = 0; i < 4; ++i) {
            int chunk = wave * 4 + i;
            int row = chunk * 8 + srow;
            gload_lds16(abase + (size_t)row * M_ + k0 + scol, As + chunk * 512);
            gload_lds16(bbase + (size_t)row * M_ + k0 + scol, Bs + chunk * 512);
        }
        __syncthreads();

        #pragma unroll
        for (int ks = 0; ks < 2; ++ks) {
            short8 af[4], bf[4];
            #pragma unroll
            for (int mi = 0; mi < 4; ++mi)
                af[mi] = *reinterpret_cast<const short8*>(
                    &As[(wm + mi * 16 + lr) * 64 +
                        ((ks * 32 + lg * 8) ^ ((lr & 7) << 3))]);
            #pragma unroll
            for (int ni = 0; ni < 4; ++ni)
                bf[ni] = *reinterpret_cast<const short8*>(
                    &Bs[(wl + ni * 16 + lr) * 64 +
                        ((ks * 32 + lg * 8) ^ ((lr & 7) << 3))]);
            #pragma unroll
            for (int mi = 0; mi < 4; ++mi)
                #pragma unroll
                for (int ni = 0; ni < 4; ++ni)
                    acc[mi][ni] = __builtin_amdgcn_mfma_f32_16x16x32_bf16(
                        af[mi], bf[ni], acc[mi][ni], 0, 0, 0);
        }
    }

    #pragma unroll
    for (int mi = 0; mi < 4; ++mi) {
        #pragma unroll
        for (int r = 0; r < 4; ++r) {
            int c = c0 + wm + mi * 16 + lg * 4 + r;
            float bias = bo[c];
            #pragma unroll
            for (int ni = 0; ni < 4; ++ni) {
                int l = l0 + wl + ni * 16 + lr;
                size_t idx = ((size_t)b * C_ + c) * L_ + l;
                out[idx] = x[idx] + lrelu(acc[mi][ni][r] + bias);
            }
        }
    }
}

// ---------------------------------------------------------------------------
extern "C" void kernel_launch(void* const* d_in, const int* in_sizes, int n_in,
                              void* d_out, int out_size, void* d_ws, size_t ws_size,
                              hipStream_t stream) {
    const float* x  = (const float*)d_in[0];
    const float* Wt = (const float*)d_in[1];
    const float* bt = (const float*)d_in[2];
    const float* Wp = (const float*)d_in[3];
    const float* bp = (const float*)d_in[4];
    const float* Wg = (const float*)d_in[5];
    const float* bg = (const float*)d_in[6];
    const float* Wo = (const float*)d_in[7];
    const float* bo = (const float*)d_in[8];
    float* out = (float*)d_out;

    unsigned short* xT    = (unsigned short*)d_ws;                  // [B][L][C]  64MB
    unsigned short* w3    = xT + (size_t)B_ * L_ * C_;              // [768][C]   3MB
    unsigned short* wob   = w3 + (size_t)M3_ * C_;                  // [C][M]     1MB
    unsigned short* theta = wob + (size_t)C_ * M_;                  // theta_cm   8MB
    unsigned short* phi   = theta + (size_t)B_ * L_ * M_;           // [B][L][M]  8MB
    unsigned short* gammaT= phi   + (size_t)B_ * L_ * M_;           // gamma_v    8MB

    unsigned short* yp = xT;     // [SPLIT][B][L][M] bf16, 32MB (xT dead after proj)
    float* rsp = (float*)w3;     // [SPLIT][B][L]    fp32 (w3 dead after proj)
    unsigned short* yb = theta;  // [B][L][M] bf16 (theta dead after attn)

    prep_x<<<dim3(L_ / 64, C_ / 32, B_), 256, 0, stream>>>(x, xT);
    prep_w<<<dim3(2097152 / 8 / 256), 256, 0, stream>>>(Wt, Wp, Wg, Wo, w3, wob);
    proj_kernel<<<dim3(L_ / 128, M3_ / 128, B_), 256, 0, stream>>>(
        w3, bt, bp, bg, xT, theta, phi, gammaT);
    attn_kernel<<<dim3(L_ / 128, SPLIT_, B_), 256, 0, stream>>>(
        phi, theta, gammaT, yp, rsp);
    reduce_kernel<<<dim3((B_ * L_ * M_ / 8) / 256), 256, 0, stream>>>(yp, rsp, yb);
    out_kernel<<<dim3(L_ / 128, C_ / 128, B_), 256, 0, stream>>>(x, wob, bo, yb, out);
}